// Round 3
// baseline (115.052 us; speedup 1.0000x reference)
//
#include <hip/hip_runtime.h>
#include <hip/hip_bf16.h>
#include <cstdint>

#define B_ 4096
#define D_ 256
#define M_ 60
#define NT 64            // 64x64 output tiles -> 64 tiles per dim
#define NTILES 2080      // NT*(NT+1)/2 upper-triangle tiles
#define NBLK 520         // 4 tiles (one per wave) per 256-thread block

typedef unsigned long long u64;
typedef short bf16x8 __attribute__((ext_vector_type(8)));   // 8 bf16 = 4 VGPRs
typedef float f32x4 __attribute__((ext_vector_type(4)));

__device__ __forceinline__ unsigned short f2bf(float x) {
    __hip_bfloat16 b = __float2bfloat16(x);
    return __builtin_bit_cast(unsigned short, b);
}

// ---------- prep: bf16 cast of raw rep, inv-norm*sqrt(10), code masks, acc init ----------
// 1024 blocks x 256 threads; wave w handles row blockIdx*4 + w.
__global__ __launch_bounds__(256) void prep_kernel(
    const float* __restrict__ rep, const int* __restrict__ codes,
    unsigned short* __restrict__ nb, float* __restrict__ invs,
    u64* __restrict__ lo, u64* __restrict__ hi, int* __restrict__ cnt,
    u64* __restrict__ accblk /* 33 x 8B: T[8],Pe[8],Ps[8],C[8],done */) {
    const int w = threadIdx.x >> 6;
    const int lane = threadIdx.x & 63;
    const int row = blockIdx.x * 4 + w;

    float4 v = ((const float4*)(rep + (size_t)row * D_))[lane];
    float ss = v.x * v.x + v.y * v.y + v.z * v.z + v.w * v.w;
#pragma unroll
    for (int off = 32; off > 0; off >>= 1) ss += __shfl_down(ss, off);
    ss = __shfl(ss, 0);

    // store RAW bf16 (normalization folded into epilogue scale)
    ushort4 o;
    o.x = f2bf(v.x); o.y = f2bf(v.y); o.z = f2bf(v.z); o.w = f2bf(v.w);
    ((ushort4*)(nb + (size_t)row * D_))[lane] = o;

    // code membership mask via wave-OR reduction (no LDS atomics)
    u64 l = 0, h = 0;
    if (lane < M_) {
        int c = codes[row * M_ + lane];
        if (c < 64) l = 1ull << c;
        else        h = 1ull << (c - 64);
    }
#pragma unroll
    for (int off = 32; off > 0; off >>= 1) {
        l |= __shfl_down(l, off);
        h |= __shfl_down(h, off);
    }
    if (lane == 0) {
        invs[row] = (1.0f / sqrtf(ss)) * 3.16227766016838f;  // inv_norm * sqrt(1/T)
        lo[row] = l; hi[row] = h;
        cnt[row] = __popcll(l) + __popcll(h);
    }
    if (blockIdx.x == 0 && threadIdx.x < 33) accblk[threadIdx.x] = 0ull;
}

// ---------- fused: barrier-free MFMA sim + jaccard + reduction + last-block finalize ----
__global__ __launch_bounds__(256) void fused_kernel(
    const unsigned short* __restrict__ Nb, const float* __restrict__ invs,
    const u64* __restrict__ lo, const u64* __restrict__ hi, const int* __restrict__ cnt,
    double* __restrict__ accT, double* __restrict__ accPe, double* __restrict__ accPs,
    u64* __restrict__ accC, u64* __restrict__ done, float* __restrict__ out) {
    const int tid = threadIdx.x;
    const int lane = tid & 63;
    const int w = tid >> 6;
    const int quad = lane >> 4;
    const int l15 = lane & 15;

    // wave -> upper-triangle 64-tile (bi, bj)
    int q = blockIdx.x * 4 + w;
    int bi = 0;
    while (q >= NT - bi) { q -= NT - bi; bi++; }
    const int bj = bi + q;
    const int rowA = bi * 64, rowB = bj * 64;

    // ---- GEMM: direct-from-global fragments, no LDS, no barriers ----
    f32x4 acc[4][4] = {};
#pragma unroll
    for (int g = 0; g < 8; g++) {
        const int koff = g * 32 + quad * 8;   // A[m][k=quad*8+j] fragment layout
        bf16x8 a[4], b[4];
#pragma unroll
        for (int t = 0; t < 4; t++) {
            a[t] = *(const bf16x8*)(Nb + (size_t)(rowA + t * 16 + l15) * D_ + koff);
            b[t] = *(const bf16x8*)(Nb + (size_t)(rowB + t * 16 + l15) * D_ + koff);
        }
#pragma unroll
        for (int i = 0; i < 4; i++)
#pragma unroll
            for (int j = 0; j < 4; j++)
                acc[i][j] = __builtin_amdgcn_mfma_f32_16x16x32_bf16(a[i], b[j], acc[i][j], 0, 0, 0);
    }

    // ---- epilogue: scale, exp, jaccard, partial sums ----
    // C/D layout: col = lane&15, row = quad*4 + reg
    int colg[4]; u64 jl[4], jh[4]; int jc[4]; float ib[4];
#pragma unroll
    for (int nt = 0; nt < 4; nt++) {
        int cg = rowB + nt * 16 + l15;
        colg[nt] = cg; jl[nt] = lo[cg]; jh[nt] = hi[cg]; jc[nt] = cnt[cg];
        ib[nt] = invs[cg];
    }

    float t_sum = 0.0f, p_exp = 0.0f, p_s = 0.0f;
    int p_cnt = 0;
#pragma unroll
    for (int mt = 0; mt < 4; mt++) {
        const int rbase = rowA + mt * 16 + quad * 4;
        u64 al[4], ah[4]; int ac[4]; float ia[4];
#pragma unroll
        for (int r = 0; r < 4; r++) {
            al[r] = lo[rbase + r]; ah[r] = hi[rbase + r];
            ac[r] = cnt[rbase + r]; ia[r] = invs[rbase + r];
        }
#pragma unroll
        for (int nt = 0; nt < 4; nt++) {
#pragma unroll
            for (int r = 0; r < 4; r++) {
                float s = acc[mt][nt][r] * ia[r] * ib[nt];   // dot * inv_i*inv_j*10
                float es = __expf(s);
                t_sum += es;
                int inter = __popcll(al[r] & jl[nt]) + __popcll(ah[r] & jh[nt]);
                int uni = ac[r] + jc[nt] - inter;
                if ((10 * inter > 3 * uni) && (rbase + r != colg[nt])) {
                    p_exp += es; p_s += s; p_cnt++;
                }
            }
        }
    }

    // symmetry: off-diagonal tiles count twice
    const float scale = (bi == bj) ? 1.0f : 2.0f;
    double dt = (double)t_sum * scale;
    double dpe = (double)p_exp * scale;
    double dps = (double)p_s * scale;
    int dc = p_cnt * ((bi == bj) ? 1 : 2);

#pragma unroll
    for (int off = 32; off > 0; off >>= 1) {
        dt += __shfl_down(dt, off);
        dpe += __shfl_down(dpe, off);
        dps += __shfl_down(dps, off);
        dc += __shfl_down(dc, off);
    }
    __shared__ double redT[4], redPe[4], redPs[4];
    __shared__ int redC[4];
    if (lane == 0) { redT[w] = dt; redPe[w] = dpe; redPs[w] = dps; redC[w] = dc; }
    __syncthreads();
    if (tid == 0) {
        double T = 0, Pe = 0, Ps = 0;
        long long C = 0;
        for (int i = 0; i < 4; i++) { T += redT[i]; Pe += redPe[i]; Ps += redPs[i]; C += redC[i]; }
        const int slot = blockIdx.x & 7;
        atomicAdd(&accT[slot], T);
        atomicAdd(&accPe[slot], Pe);
        atomicAdd(&accPs[slot], Ps);
        atomicAdd(&accC[slot], (u64)C);
        __threadfence();
        u64 old = atomicAdd(done, 1ull);
        if (old == (u64)(NBLK - 1)) {
            // last block: device-scope atomic reads (safe across XCD L2s)
            double Tt = 0, Pet = 0, Pst = 0, n = 0;
            for (int i = 0; i < 8; i++) {
                Tt  += atomicAdd(&accT[i], 0.0);
                Pet += atomicAdd(&accPe[i], 0.0);
                Pst += atomicAdd(&accPs[i], 0.0);
                n   += (double)atomicAdd(&accC[i], 0ull);
            }
            double neg = Tt - Pet;   // negatives incl. diagonal
            double loss = (n > 0.0) ? log(neg) + (Pet / neg - Pst) / n : 0.0;
            out[0] = (float)loss;
        }
    }
}

extern "C" void kernel_launch(void* const* d_in, const int* in_sizes, int n_in,
                              void* d_out, int out_size, void* d_ws, size_t ws_size,
                              hipStream_t stream) {
    const float* rep = (const float*)d_in[0];
    const int* codes = (const int*)d_in[1];
    // d_in[2] = labels, unused by the reference computation

    // workspace layout
    unsigned short* nb = (unsigned short*)d_ws;                // 2 MiB raw bf16
    char* p = (char*)d_ws + (size_t)B_ * D_ * 2;
    float* invs = (float*)p;                                   // 16 KiB
    u64* lo = (u64*)(invs + B_);                               // 32 KiB
    u64* hi = lo + B_;                                         // 32 KiB
    int* cnt = (int*)(hi + B_);                                // 16 KiB
    u64* accblk = (u64*)(cnt + B_);                            // 33 x 8B
    double* accT = (double*)accblk;
    double* accPe = accT + 8;
    double* accPs = accPe + 8;
    u64* accC = (u64*)(accPs + 8);
    u64* done = accC + 8;

    float* out = (float*)d_out;

    prep_kernel<<<B_ / 4, 256, 0, stream>>>(rep, codes, nb, invs, lo, hi, cnt, accblk);
    fused_kernel<<<NBLK, 256, 0, stream>>>(nb, invs, lo, hi, cnt,
                                           accT, accPe, accPs, accC, done, out);
}

// Round 4
// 110.773 us; speedup vs baseline: 1.0386x; 1.0386x over previous
//
#include <hip/hip_runtime.h>
#include <hip/hip_bf16.h>
#include <cstdint>

#define B_ 4096
#define D_ 256
#define M_ 60
#define NT 64            // 64x64 output tiles -> 64 tiles per dim
#define NTILES 2080      // NT*(NT+1)/2 upper-triangle tiles, 1 block each

typedef unsigned long long u64;
typedef short bf16x8 __attribute__((ext_vector_type(8)));   // 8 bf16 = 4 VGPRs
typedef float f32x4 __attribute__((ext_vector_type(4)));

__device__ __forceinline__ unsigned short f2bf(float x) {
    __hip_bfloat16 b = __float2bfloat16(x);
    return __builtin_bit_cast(unsigned short, b);
}

// ---------- prep: bf16 cast of raw rep, inv-norm*sqrt(10), code masks, slot init ----------
// 1024 blocks x 256 threads; wave w handles row blockIdx*4 + w.
__global__ __launch_bounds__(256) void prep_kernel(
    const float* __restrict__ rep, const int* __restrict__ codes,
    unsigned short* __restrict__ nb, float* __restrict__ invs,
    u64* __restrict__ lo, u64* __restrict__ hi, int* __restrict__ cnt,
    u64* __restrict__ accblk /* 513 x 8B: 64 slots x 8 doubles + done */) {
    const int w = threadIdx.x >> 6;
    const int lane = threadIdx.x & 63;
    const int row = blockIdx.x * 4 + w;

    float4 v = ((const float4*)(rep + (size_t)row * D_))[lane];
    float ss = v.x * v.x + v.y * v.y + v.z * v.z + v.w * v.w;
#pragma unroll
    for (int off = 32; off > 0; off >>= 1) ss += __shfl_down(ss, off);
    ss = __shfl(ss, 0);

    // store RAW bf16 (normalization folded into epilogue scale)
    ushort4 o;
    o.x = f2bf(v.x); o.y = f2bf(v.y); o.z = f2bf(v.z); o.w = f2bf(v.w);
    ((ushort4*)(nb + (size_t)row * D_))[lane] = o;

    // code membership mask via wave-OR reduction
    u64 l = 0, h = 0;
    if (lane < M_) {
        int c = codes[row * M_ + lane];
        if (c < 64) l = 1ull << c;
        else        h = 1ull << (c - 64);
    }
#pragma unroll
    for (int off = 32; off > 0; off >>= 1) {
        l |= __shfl_down(l, off);
        h |= __shfl_down(h, off);
    }
    if (lane == 0) {
        invs[row] = (1.0f / sqrtf(ss)) * 3.16227766016838f;  // inv_norm * sqrt(1/T)
        lo[row] = l; hi[row] = h;
        cnt[row] = __popcll(l) + __popcll(h);
    }
    if (blockIdx.x == 0) {
        accblk[threadIdx.x] = 0ull;          // slots 0..255
        accblk[256 + threadIdx.x] = 0ull;    // slots 256..511
        if (threadIdx.x == 0) accblk[512] = 0ull;  // done counter
    }
}

// ---------- fused: full-K LDS stage (1 barrier), MFMA, jaccard, slot-atomics, last-block finalize ----------
__global__ __launch_bounds__(256) void fused_kernel(
    const unsigned short* __restrict__ Nb, const float* __restrict__ invs,
    const u64* __restrict__ lo, const u64* __restrict__ hi, const int* __restrict__ cnt,
    double* __restrict__ accs /* 64 slots x 8 doubles */, u64* __restrict__ done,
    float* __restrict__ out) {
    // A tile: 64 rows x 256 bf16 (512 B/row, 32 chunks of 16 B), XOR-swizzled. B same.
    __shared__ __attribute__((aligned(16))) char smem[2 * 64 * 512];  // 64 KB
    char* As = smem;
    char* Bs = smem + 64 * 512;

    const int tid = threadIdx.x;
    const int lane = tid & 63;
    const int w = tid >> 6;
    const int quad = lane >> 4;
    const int l15 = lane & 15;

    // block -> upper-triangle 64-tile (bi, bj)
    int q = blockIdx.x, bi = 0;
    while (q >= NT - bi) { q -= NT - bi; bi++; }
    const int bj = bi + q;
    const int rowA = bi * 64, rowB = bj * 64;

    // ---- stage full K: 8 iters x 4 waves x 64 lanes x 16 B per operand ----
    // physical chunk P = region*64 + lane; row = P>>5, pc = P&31; logical chunk lc = pc ^ (row&31)
#pragma unroll
    for (int it = 0; it < 8; it++) {
        int region = it * 4 + w;
        int P = region * 64 + lane;
        int row = P >> 5;
        int lc = (P & 31) ^ (row & 31);
        const unsigned short* gA = Nb + (size_t)(rowA + row) * D_ + lc * 8;
        const unsigned short* gB = Nb + (size_t)(rowB + row) * D_ + lc * 8;
        __builtin_amdgcn_global_load_lds(
            (const __attribute__((address_space(1))) void*)gA,
            (__attribute__((address_space(3))) void*)(As + region * 1024), 16, 0, 0);
        __builtin_amdgcn_global_load_lds(
            (const __attribute__((address_space(1))) void*)gB,
            (__attribute__((address_space(3))) void*)(Bs + region * 1024), 16, 0, 0);
    }
    __syncthreads();   // the ONLY staging barrier

    // ---- compute: wave w owns 32x32 quadrant (wr, wc); 8 K-groups x 4 MFMA ----
    const int wr = w >> 1, wc = w & 1;
    f32x4 acc[2][2] = {};
#pragma unroll
    for (int g = 0; g < 8; g++) {
        const int lc = g * 4 + quad;        // logical chunk for A[m][k=quad*8+j]
        bf16x8 a[2], b[2];
#pragma unroll
        for (int t = 0; t < 2; t++) {
            int rA = wr * 32 + t * 16 + l15;
            a[t] = *(const bf16x8*)(As + rA * 512 + ((lc ^ (rA & 31)) * 16));
            int rB = wc * 32 + t * 16 + l15;
            b[t] = *(const bf16x8*)(Bs + rB * 512 + ((lc ^ (rB & 31)) * 16));
        }
#pragma unroll
        for (int i = 0; i < 2; i++)
#pragma unroll
            for (int j = 0; j < 2; j++)
                acc[i][j] = __builtin_amdgcn_mfma_f32_16x16x32_bf16(a[i], b[j], acc[i][j], 0, 0, 0);
    }

    // ---- epilogue: scale, exp, jaccard, partial sums ----
    // C/D layout: col = lane&15, row = quad*4 + reg
    int colg[2]; u64 jl[2], jh[2]; int jc[2]; float ib[2];
#pragma unroll
    for (int nt = 0; nt < 2; nt++) {
        int cg = rowB + wc * 32 + nt * 16 + l15;
        colg[nt] = cg; jl[nt] = lo[cg]; jh[nt] = hi[cg]; jc[nt] = cnt[cg];
        ib[nt] = invs[cg];
    }

    float t_sum = 0.0f, p_exp = 0.0f, p_s = 0.0f;
    int p_cnt = 0;
#pragma unroll
    for (int mt = 0; mt < 2; mt++) {
        const int rbase = rowA + wr * 32 + mt * 16 + quad * 4;
        u64 al[4], ah[4]; int ac[4]; float ia[4];
#pragma unroll
        for (int r = 0; r < 4; r++) {
            al[r] = lo[rbase + r]; ah[r] = hi[rbase + r];
            ac[r] = cnt[rbase + r]; ia[r] = invs[rbase + r];
        }
#pragma unroll
        for (int nt = 0; nt < 2; nt++) {
#pragma unroll
            for (int r = 0; r < 4; r++) {
                float s = acc[mt][nt][r] * ia[r] * ib[nt];   // dot * inv_i*inv_j*10
                float es = __expf(s);
                t_sum += es;
                int inter = __popcll(al[r] & jl[nt]) + __popcll(ah[r] & jh[nt]);
                int uni = ac[r] + jc[nt] - inter;
                if ((10 * inter > 3 * uni) && (rbase + r != colg[nt])) {
                    p_exp += es; p_s += s; p_cnt++;
                }
            }
        }
    }

    // symmetry: off-diagonal tiles count twice
    const float scale = (bi == bj) ? 1.0f : 2.0f;
    double dt = (double)t_sum * scale;
    double dpe = (double)p_exp * scale;
    double dps = (double)p_s * scale;
    int dc = p_cnt * ((bi == bj) ? 1 : 2);

#pragma unroll
    for (int off = 32; off > 0; off >>= 1) {
        dt += __shfl_down(dt, off);
        dpe += __shfl_down(dpe, off);
        dps += __shfl_down(dps, off);
        dc += __shfl_down(dc, off);
    }
    __shared__ double redT[4], redPe[4], redPs[4];
    __shared__ int redC[4];
    __shared__ int isLastSh;
    if (lane == 0) { redT[w] = dt; redPe[w] = dpe; redPs[w] = dps; redC[w] = dc; }
    __syncthreads();
    if (tid == 0) {
        double T = 0, Pe = 0, Ps = 0;
        long long C = 0;
        for (int i = 0; i < 4; i++) { T += redT[i]; Pe += redPe[i]; Ps += redPs[i]; C += redC[i]; }
        double* slot = accs + (size_t)(blockIdx.x & 63) * 8;   // own 64B cache line
        atomicAdd(&slot[0], T);
        atomicAdd(&slot[1], Pe);
        atomicAdd(&slot[2], Ps);
        atomicAdd(&slot[3], (double)C);
        __threadfence();
        u64 old = atomicAdd(done, 1ull);
        isLastSh = (old == (u64)(NTILES - 1)) ? 1 : 0;
    }
    __syncthreads();
    if (isLastSh && w == 0) {
        // last block: one wave, lane L reads slot L via device-scope atomic-reads
        double v0 = atomicAdd(&accs[lane * 8 + 0], 0.0);
        double v1 = atomicAdd(&accs[lane * 8 + 1], 0.0);
        double v2 = atomicAdd(&accs[lane * 8 + 2], 0.0);
        double v3 = atomicAdd(&accs[lane * 8 + 3], 0.0);
#pragma unroll
        for (int off = 32; off > 0; off >>= 1) {
            v0 += __shfl_down(v0, off);
            v1 += __shfl_down(v1, off);
            v2 += __shfl_down(v2, off);
            v3 += __shfl_down(v3, off);
        }
        if (lane == 0) {
            double neg = v0 - v1;   // negatives incl. diagonal
            double loss = (v3 > 0.0) ? log(neg) + (v1 / neg - v2) / v3 : 0.0;
            out[0] = (float)loss;
        }
    }
}

extern "C" void kernel_launch(void* const* d_in, const int* in_sizes, int n_in,
                              void* d_out, int out_size, void* d_ws, size_t ws_size,
                              hipStream_t stream) {
    const float* rep = (const float*)d_in[0];
    const int* codes = (const int*)d_in[1];
    // d_in[2] = labels, unused by the reference computation

    // workspace layout
    unsigned short* nb = (unsigned short*)d_ws;                // 2 MiB raw bf16
    char* p = (char*)d_ws + (size_t)B_ * D_ * 2;
    float* invs = (float*)p;                                   // 16 KiB
    u64* lo = (u64*)(invs + B_);                               // 32 KiB
    u64* hi = lo + B_;                                         // 32 KiB
    int* cnt = (int*)(hi + B_);                                // 16 KiB
    u64* accblk = (u64*)(cnt + B_);                            // 513 x 8B
    double* accs = (double*)accblk;                            // 64 slots x 8 doubles
    u64* done = accblk + 512;

    float* out = (float*)d_out;

    prep_kernel<<<B_ / 4, 256, 0, stream>>>(rep, codes, nb, invs, lo, hi, cnt, accblk);
    fused_kernel<<<NTILES, 256, 0, stream>>>(nb, invs, lo, hi, cnt, accs, done, out);
}

// Round 5
// 83.876 us; speedup vs baseline: 1.3717x; 1.3207x over previous
//
#include <hip/hip_runtime.h>
#include <hip/hip_bf16.h>
#include <cstdint>

#define B_ 4096
#define D_ 256
#define M_ 60
#define NT_ 32          // 128-tiles per dimension
#define NBLK 528        // NT_*(NT_+1)/2 upper-triangle tiles
#define BM 128
#define BK 64           // bf16 elements per K-step (128 bytes/row)

typedef unsigned long long u64;
typedef short bf16x8 __attribute__((ext_vector_type(8)));   // 8 bf16 = 4 VGPRs
typedef float f32x4 __attribute__((ext_vector_type(4)));

__device__ __forceinline__ unsigned short f2bf(float x) {
    __hip_bfloat16 b = __float2bfloat16(x);
    return __builtin_bit_cast(unsigned short, b);
}

// ---------- prep: bf16 cast of raw rep, inv-norm*sqrt(10), code masks ----------
// 1024 blocks x 256 threads; wave w handles row blockIdx*4 + w.
__global__ __launch_bounds__(256) void prep_kernel(
    const float* __restrict__ rep, const int* __restrict__ codes,
    unsigned short* __restrict__ nb, float* __restrict__ invs,
    u64* __restrict__ lo, u64* __restrict__ hi, int* __restrict__ cnt) {
    const int w = threadIdx.x >> 6;
    const int lane = threadIdx.x & 63;
    const int row = blockIdx.x * 4 + w;

    float4 v = ((const float4*)(rep + (size_t)row * D_))[lane];
    float ss = v.x * v.x + v.y * v.y + v.z * v.z + v.w * v.w;
#pragma unroll
    for (int off = 32; off > 0; off >>= 1) ss += __shfl_down(ss, off);
    ss = __shfl(ss, 0);

    // store RAW bf16 (normalization folded into epilogue scale)
    ushort4 o;
    o.x = f2bf(v.x); o.y = f2bf(v.y); o.z = f2bf(v.z); o.w = f2bf(v.w);
    ((ushort4*)(nb + (size_t)row * D_))[lane] = o;

    // code membership mask via wave-OR reduction
    u64 l = 0, h = 0;
    if (lane < M_) {
        int c = codes[row * M_ + lane];
        if (c < 64) l = 1ull << c;
        else        h = 1ull << (c - 64);
    }
#pragma unroll
    for (int off = 32; off > 0; off >>= 1) {
        l |= __shfl_down(l, off);
        h |= __shfl_down(h, off);
    }
    if (lane == 0) {
        invs[row] = (1.0f / sqrtf(ss)) * 3.16227766016838f;  // inv_norm * sqrt(1/T)
        lo[row] = l; hi[row] = h;
        cnt[row] = __popcll(l) + __popcll(h);
    }
}

// ---------- fused: bf16 MFMA sim-GEMM (round-2 structure) + jaccard + partial STORE ----------
__global__ __launch_bounds__(256) void fused_kernel(
    const unsigned short* __restrict__ Nb, const float* __restrict__ invs,
    const u64* __restrict__ lo, const u64* __restrict__ hi, const int* __restrict__ cnt,
    double* __restrict__ partials /* NBLK x 8 doubles (64B stride) */) {
    // 16 KB per operand tile: 128 rows x 64 bf16 (128 B/row), XOR-swizzled 16B chunks
    __shared__ __attribute__((aligned(16))) char smem[2 * BM * BK * 2];
    char* AsB = smem;
    char* BsB = smem + BM * BK * 2;

    const int tid = threadIdx.x;
    const int lane = tid & 63;
    const int w = tid >> 6;
    const int wr = w >> 1, wc = w & 1;
    const int quad = lane >> 4;
    const int l15 = lane & 15;
    const int l7 = lane & 7;

    // block -> (bi, bj) with bj >= bi
    int q = blockIdx.x, bi = 0;
    while (q >= NT_ - bi) { q -= NT_ - bi; bi++; }
    const int bj = bi + q;
    const int rowA = bi * BM, rowB = bj * BM;

    f32x4 accf[4][4] = {};

    for (int k0 = 0; k0 < D_; k0 += BK) {
        __syncthreads();
        // stage A and B tiles via async global->LDS, 16B per lane
        // physical chunk P = region*64 + lane; row = P>>3, pc = P&7, logical chunk c = pc ^ (row&7)
#pragma unroll
        for (int it = 0; it < 4; it++) {
            int region = it * 4 + w;
            int P = region * 64 + lane;
            int row = P >> 3;
            int c = (P & 7) ^ (row & 7);
            const unsigned short* gA = Nb + (size_t)(rowA + row) * D_ + k0 + c * 8;
            const unsigned short* gB = Nb + (size_t)(rowB + row) * D_ + k0 + c * 8;
            __builtin_amdgcn_global_load_lds(
                (const __attribute__((address_space(1))) void*)gA,
                (__attribute__((address_space(3))) void*)(AsB + region * 1024), 16, 0, 0);
            __builtin_amdgcn_global_load_lds(
                (const __attribute__((address_space(1))) void*)gB,
                (__attribute__((address_space(3))) void*)(BsB + region * 1024), 16, 0, 0);
        }
        __syncthreads();
        // compute: 2 mfma-K groups x 16 mfma
#pragma unroll
        for (int kk = 0; kk < 2; kk++) {
            int pc = (kk * 4 + quad) ^ l7;   // swizzled chunk for this lane's fragment
            bf16x8 a[4], b[4];
#pragma unroll
            for (int t = 0; t < 4; t++) {
                int rA = wr * 64 + t * 16 + l15;
                a[t] = *(const bf16x8*)(AsB + rA * 128 + pc * 16);
                int rB = wc * 64 + t * 16 + l15;
                b[t] = *(const bf16x8*)(BsB + rB * 128 + pc * 16);
            }
#pragma unroll
            for (int i = 0; i < 4; i++)
#pragma unroll
                for (int j = 0; j < 4; j++)
                    accf[i][j] = __builtin_amdgcn_mfma_f32_16x16x32_bf16(a[i], b[j], accf[i][j], 0, 0, 0);
        }
    }

    // ---------- epilogue ----------
    // C/D layout (16x16): col = lane&15, row = quad*4 + reg
    int colg[4]; u64 jl[4], jh[4]; int jc[4]; float ib[4];
#pragma unroll
    for (int nt = 0; nt < 4; nt++) {
        int cg = rowB + wc * 64 + nt * 16 + l15;
        colg[nt] = cg; jl[nt] = lo[cg]; jh[nt] = hi[cg]; jc[nt] = cnt[cg];
        ib[nt] = invs[cg];
    }

    float t_sum = 0.0f, p_exp = 0.0f, p_s = 0.0f;
    int p_cnt = 0;
#pragma unroll
    for (int mt = 0; mt < 4; mt++) {
        int rbase = rowA + wr * 64 + mt * 16 + quad * 4;
        u64 al[4], ah[4]; int ac[4]; float ia[4];
#pragma unroll
        for (int r = 0; r < 4; r++) {
            al[r] = lo[rbase + r]; ah[r] = hi[rbase + r];
            ac[r] = cnt[rbase + r]; ia[r] = invs[rbase + r];
        }
#pragma unroll
        for (int nt = 0; nt < 4; nt++) {
#pragma unroll
            for (int r = 0; r < 4; r++) {
                float s = accf[mt][nt][r] * ia[r] * ib[nt];   // dot * inv_i*inv_j*10
                float es = __expf(s);
                t_sum += es;
                int inter = __popcll(al[r] & jl[nt]) + __popcll(ah[r] & jh[nt]);
                int uni = ac[r] + jc[nt] - inter;
                if ((10 * inter > 3 * uni) && (rbase + r != colg[nt])) {
                    p_exp += es; p_s += s; p_cnt++;
                }
            }
        }
    }

    // per-wave float reduction (cheap), then LDS, then ONE uncontended store per block
#pragma unroll
    for (int off = 32; off > 0; off >>= 1) {
        t_sum += __shfl_down(t_sum, off);
        p_exp += __shfl_down(p_exp, off);
        p_s   += __shfl_down(p_s, off);
        p_cnt += __shfl_down(p_cnt, off);
    }
    __shared__ float redT[4], redPe[4], redPs[4];
    __shared__ int redC[4];
    if (lane == 0) { redT[w] = t_sum; redPe[w] = p_exp; redPs[w] = p_s; redC[w] = p_cnt; }
    __syncthreads();
    if (tid == 0) {
        double T = 0, Pe = 0, Ps = 0;
        long long C = 0;
        for (int i = 0; i < 4; i++) {
            T += (double)redT[i]; Pe += (double)redPe[i];
            Ps += (double)redPs[i]; C += redC[i];
        }
        double scale = (bi == bj) ? 1.0 : 2.0;   // symmetry: off-diagonal counts twice
        double* dst = partials + (size_t)blockIdx.x * 8;
        dst[0] = T * scale;
        dst[1] = Pe * scale;
        dst[2] = Ps * scale;
        dst[3] = (double)C * scale;
    }
}

// ---------- finalize: reduce 528 partials, compute loss ----------
__global__ __launch_bounds__(256) void finalize_kernel(
    const double* __restrict__ partials, float* __restrict__ out) {
    const int tid = threadIdx.x;
    const int lane = tid & 63;
    const int w = tid >> 6;
    double T = 0, Pe = 0, Ps = 0, C = 0;
    for (int i = tid; i < NBLK; i += 256) {
        const double* src = partials + (size_t)i * 8;
        T += src[0]; Pe += src[1]; Ps += src[2]; C += src[3];
    }
#pragma unroll
    for (int off = 32; off > 0; off >>= 1) {
        T += __shfl_down(T, off);
        Pe += __shfl_down(Pe, off);
        Ps += __shfl_down(Ps, off);
        C += __shfl_down(C, off);
    }
    __shared__ double redT[4], redPe[4], redPs[4], redC[4];
    if (lane == 0) { redT[w] = T; redPe[w] = Pe; redPs[w] = Ps; redC[w] = C; }
    __syncthreads();
    if (tid == 0) {
        double Tt = 0, Pet = 0, Pst = 0, n = 0;
        for (int i = 0; i < 4; i++) { Tt += redT[i]; Pet += redPe[i]; Pst += redPs[i]; n += redC[i]; }
        double neg = Tt - Pet;   // negatives incl. diagonal
        double loss = (n > 0.0) ? log(neg) + (Pet / neg - Pst) / n : 0.0;
        out[0] = (float)loss;
    }
}

extern "C" void kernel_launch(void* const* d_in, const int* in_sizes, int n_in,
                              void* d_out, int out_size, void* d_ws, size_t ws_size,
                              hipStream_t stream) {
    const float* rep = (const float*)d_in[0];
    const int* codes = (const int*)d_in[1];
    // d_in[2] = labels, unused by the reference computation

    // workspace layout
    unsigned short* nb = (unsigned short*)d_ws;                // 2 MiB raw bf16
    char* p = (char*)d_ws + (size_t)B_ * D_ * 2;
    float* invs = (float*)p;                                   // 16 KiB
    u64* lo = (u64*)(invs + B_);                               // 32 KiB
    u64* hi = lo + B_;                                         // 32 KiB
    int* cnt = (int*)(hi + B_);                                // 16 KiB
    double* partials = (double*)(cnt + B_);                    // 528 x 8 doubles = 33 KiB

    float* out = (float*)d_out;

    prep_kernel<<<B_ / 4, 256, 0, stream>>>(rep, codes, nb, invs, lo, hi, cnt);
    fused_kernel<<<NBLK, 256, 0, stream>>>(nb, invs, lo, hi, cnt, partials);
    finalize_kernel<<<1, 256, 0, stream>>>(partials, out);
}